// Round 1
// baseline (11911.620 us; speedup 1.0000x reference)
//
#include <hip/hip_runtime.h>

// ---------------------------------------------------------------------------
// 2-layer Elman RNN LM forward on MI355X.
// Pipeline: transpose weights (f32->bf16, [K][N]->[N][K]) -> embed gather ->
// U0 GEMM -> persistent rec layer0 -> U1 GEMM -> rec layer1 -> logits GEMM
// (bf16 MFMA, f32 out + bias) -> row logsumexp -> mean loss.
// Recurrence: 128 persistent WGs, spin barrier on device-scope atomic counter,
// h exchanged via agent-scope (LLC-coherent) atomics, ping-pong h buffers.
// ---------------------------------------------------------------------------

#define H_DIM 1024
#define B_SZ 8
#define T_SZ 512
#define V_SZ 50257
#define V_PAD 50304
#define REC_WGS 128
#define REC_THREADS 512

typedef __attribute__((ext_vector_type(8))) short bf16x8;
typedef __attribute__((ext_vector_type(4))) float f32x4;

__device__ __forceinline__ unsigned short f2bf(float f) {
  unsigned int u = __float_as_uint(f);
  u += 0x7fffu + ((u >> 16) & 1u);   // round-to-nearest-even
  return (unsigned short)(u >> 16);
}
__device__ __forceinline__ float bf2f(unsigned short h) {
  return __uint_as_float(((unsigned int)h) << 16);
}

__device__ __forceinline__ void gload_lds16(const void* g, void* l) {
  __builtin_amdgcn_global_load_lds(
      (const __attribute__((address_space(1))) void*)g,
      (__attribute__((address_space(3))) void*)l, 16, 0, 0);
}

// ---------------- transpose f32 [K][N] -> bf16 [Npad][K] (zero-fill pad) ----
__global__ __launch_bounds__(256) void k_transpose(
    const float* __restrict__ in, unsigned short* __restrict__ out,
    int K, int N, int Npad)
{
  __shared__ float tile[32][33];
  const int n0 = blockIdx.x * 32, k0 = blockIdx.y * 32;
  const int tx = threadIdx.x, ty = threadIdx.y;
#pragma unroll
  for (int jj = 0; jj < 4; ++jj) {
    int k = k0 + ty + jj * 8, n = n0 + tx;
    tile[ty + jj * 8][tx] = (n < N) ? in[(size_t)k * N + n] : 0.f;
  }
  __syncthreads();
#pragma unroll
  for (int jj = 0; jj < 4; ++jj) {
    int n = n0 + ty + jj * 8, k = k0 + tx;
    if (n < Npad) out[(size_t)n * K + k] = f2bf((n < N) ? tile[tx][ty + jj * 8] : 0.f);
  }
}

// ---------------- embedding gather -> time-major bf16 [T*B][512] ------------
__global__ __launch_bounds__(128) void k_embed(
    const int* __restrict__ x, const float* __restrict__ E,
    unsigned short* __restrict__ xe)
{
  const int r = blockIdx.x;            // time-major row t*8+b
  const int t = r >> 3, b = r & 7;
  const int tok = x[b * T_SZ + t];
  const float4 v = ((const float4*)(E + (size_t)tok * 512))[threadIdx.x];
  ushort4 o;
  o.x = f2bf(v.x); o.y = f2bf(v.y); o.z = f2bf(v.z); o.w = f2bf(v.w);
  *((ushort4*)(xe + (size_t)r * 512) + threadIdx.x) = o;
}

// ---------------- bf16 MFMA GEMM: C[M][N] = A[M][K] @ Bt[N][K]^T (+bias) ----
// 128x128 tile, BK=64, 4 waves (2x2 of 64x64). global_load_lds w=16, XOR
// swizzle ((row&7)<<4) applied to staging SOURCE and LDS reads (involution).
// A/B frags use the same k-slot bijection f(c,i)=c*8+i -> layout-proof.
template <bool BF16_OUT, bool BIAS>
__global__ __launch_bounds__(256) void k_gemm(
    const unsigned short* __restrict__ A, const unsigned short* __restrict__ Bt,
    void* __restrict__ Cout, const float* __restrict__ bias,
    int Nvalid, int K, int lda, int ldb, int ldc)
{
  __shared__ unsigned short As[8192];
  __shared__ unsigned short Bs[8192];
  const int tid = threadIdx.x;
  const int n0 = blockIdx.x * 128;
  const int m0 = blockIdx.y * 128;
  const int lane = tid & 63;
  const int wv = tid >> 6;
  const int wm = wv >> 1, wn = wv & 1;
  const int ln = lane & 15, cc = lane >> 4;
  f32x4 acc[4][4] = {};
  const int rr = tid >> 3;             // 0..31 row within issue group
  const int cb = (tid & 7) << 4;       // linear byte col 0..112

  for (int kb = 0; kb < K; kb += 64) {
    __syncthreads();
#pragma unroll
    for (int is = 0; is < 4; ++is) {
      int r = is * 32 + rr;
      int sb = cb ^ ((r & 7) << 4);
      gload_lds16((const char*)(A + (size_t)(m0 + r) * lda + kb) + sb,
                  &As[(is * 32 + 8 * wv) * 64]);
    }
#pragma unroll
    for (int is = 0; is < 4; ++is) {
      int r = is * 32 + rr;
      int sb = cb ^ ((r & 7) << 4);
      gload_lds16((const char*)(Bt + (size_t)(n0 + r) * ldb + kb) + sb,
                  &Bs[(is * 32 + 8 * wv) * 64]);
    }
    __syncthreads();
#pragma unroll
    for (int kk = 0; kk < 2; ++kk) {
      bf16x8 af[4], bfr[4];
      const int kslot = kk * 64 + cc * 16;
#pragma unroll
      for (int mi = 0; mi < 4; ++mi) {
        int ra = wm * 64 + mi * 16 + ln;
        af[mi] = *(const bf16x8*)((const char*)As + ra * 128 + (kslot ^ ((ra & 7) << 4)));
      }
#pragma unroll
      for (int ni = 0; ni < 4; ++ni) {
        int rb = wn * 64 + ni * 16 + ln;
        bfr[ni] = *(const bf16x8*)((const char*)Bs + rb * 128 + (kslot ^ ((rb & 7) << 4)));
      }
#pragma unroll
      for (int mi = 0; mi < 4; ++mi)
#pragma unroll
        for (int ni = 0; ni < 4; ++ni)
          acc[mi][ni] = __builtin_amdgcn_mfma_f32_16x16x32_bf16(af[mi], bfr[ni], acc[mi][ni], 0, 0, 0);
    }
  }
  // epilogue: C row = (lane>>4)*4 + reg, col = lane&15  [verified m89 layout]
#pragma unroll
  for (int ni = 0; ni < 4; ++ni) {
    const int col = n0 + wn * 64 + ni * 16 + ln;
    const bool cok = col < Nvalid;
    float bv = 0.f;
    if (BIAS && cok) bv = bias[col];
#pragma unroll
    for (int mi = 0; mi < 4; ++mi) {
#pragma unroll
      for (int i = 0; i < 4; ++i) {
        if (cok) {
          const int rowg = m0 + wm * 64 + mi * 16 + cc * 4 + i;
          if (BF16_OUT)
            ((unsigned short*)Cout)[(size_t)rowg * ldc + col] = f2bf(acc[mi][ni][i]);
          else
            ((float*)Cout)[(size_t)rowg * ldc + col] = acc[mi][ni][i] + bv;
        }
      }
    }
  }
}

// ---------------- persistent recurrence: h_t = tanh(u_t + h_{t-1} @ Whh) ----
// 128 WGs x 512 thr; WG owns 8 output cols. LDS: Whh slice f32 [8][1024] +
// h f32 [8][1024], both XOR-swizzled (k ^ (row<<2)) -> conflict-free float4.
// Exactly 64 KB LDS; partial-reduce buffer aliases hs (sync-disciplined).
__global__ __launch_bounds__(REC_THREADS) void k_rec(
    const unsigned short* __restrict__ U, const float* __restrict__ Whh,
    unsigned short* __restrict__ ys, int ost_t, int ost_b,
    float* __restrict__ hbuf, unsigned int* __restrict__ counter)
{
  __shared__ float Wsf[8192];
  __shared__ float hs_f[8192];
  float* part = hs_f;                  // alias: only live between syncs B..C
  const int tid = threadIdx.x;
  const int col0 = blockIdx.x * 8;
  for (int i = tid; i < 8192; i += REC_THREADS) {
    int j = i & 7, k = i >> 3;
    Wsf[j * 1024 + (k ^ (j << 2))] = Whh[(size_t)k * H_DIM + col0 + j];
  }
  const int b = tid & 7;
  const int j = (tid >> 3) & 7;
  const int ks = tid >> 6;             // 0..7, one per wave
  const int k0 = ks * 128;

  for (int t = 0; t < T_SZ; ++t) {
    const float* hg = hbuf + (t & 1) * 8192;     // ping-pong read buffer
    for (int i = tid; i < 8192; i += REC_THREADS) {
      float v = __hip_atomic_load(hg + i, __ATOMIC_RELAXED, __HIP_MEMORY_SCOPE_AGENT);
      int bb = i & 7, kk = i >> 3;
      hs_f[bb * 1024 + (kk ^ (bb << 2))] = v;
    }
    __syncthreads();                             // A: hs (and step-0 Wsf) ready
    float acc = 0.f;
    const float* wbase = Wsf + j * 1024;
    const float* hbase = hs_f + b * 1024;
#pragma unroll 8
    for (int k = k0; k < k0 + 128; k += 4) {
      float4 wv = *(const float4*)(wbase + (k ^ (j << 2)));
      float4 hv = *(const float4*)(hbase + (k ^ (b << 2)));
      acc = fmaf(wv.x, hv.x, acc);
      acc = fmaf(wv.y, hv.y, acc);
      acc = fmaf(wv.z, hv.z, acc);
      acc = fmaf(wv.w, hv.w, acc);
    }
    __syncthreads();                             // B: all hs reads done -> alias safe
    part[ks * 64 + j * 8 + b] = acc;
    __syncthreads();                             // C: partials ready
    if (tid < 64) {
      float s = 0.f;
#pragma unroll
      for (int q = 0; q < 8; ++q) s += part[q * 64 + j * 8 + b];
      float u = bf2f(U[(size_t)(t * B_SZ + b) * H_DIM + col0 + j]);
      float hn = tanhf(s + u);
      float* hng = hbuf + ((t + 1) & 1) * 8192;
      __hip_atomic_store(hng + (col0 + j) * 8 + b, hn, __ATOMIC_RELAXED, __HIP_MEMORY_SCOPE_AGENT);
      ys[(size_t)t * ost_t + (size_t)b * ost_b + col0 + j] = f2bf(hn);
    }
    asm volatile("s_waitcnt vmcnt(0)" ::: "memory");
    __syncthreads();                             // D: all WG stores drained
    if (tid == 0) {
      __hip_atomic_fetch_add(counter, 1u, __ATOMIC_RELEASE, __HIP_MEMORY_SCOPE_AGENT);
      unsigned tgt = (unsigned)(t + 1) * REC_WGS;
      while (__hip_atomic_load(counter, __ATOMIC_ACQUIRE, __HIP_MEMORY_SCOPE_AGENT) < tgt) {
        __builtin_amdgcn_s_sleep(2);
      }
    }
    __syncthreads();                             // E: barrier passed
  }
}

// ---------------- per-row online logsumexp -> rowloss ----------------------
__global__ __launch_bounds__(256) void k_loss_row(
    const float* __restrict__ logits, const int* __restrict__ y,
    float* __restrict__ rowloss)
{
  const int row = blockIdx.x;          // = b*T + t, matches y flat index
  const int tid = threadIdx.x;
  const float* L = logits + (size_t)row * V_SZ;
  float m = -3.4e38f, s = 0.f;
  for (int i = tid; i < V_SZ; i += 256) {
    float v = L[i];
    if (v > m) { s = s * __expf(m - v) + 1.f; m = v; }
    else s += __expf(v - m);
  }
  for (int off = 32; off > 0; off >>= 1) {
    float mo = __shfl_xor(m, off);
    float so = __shfl_xor(s, off);
    float nm = fmaxf(m, mo);
    s = s * __expf(m - nm) + so * __expf(mo - nm);
    m = nm;
  }
  __shared__ float sm[4], ss[4];
  const int wvi = tid >> 6, ln = tid & 63;
  if (ln == 0) { sm[wvi] = m; ss[wvi] = s; }
  __syncthreads();
  if (tid == 0) {
    float M = sm[0], S = ss[0];
    for (int w = 1; w < 4; ++w) {
      float nm = fmaxf(M, sm[w]);
      S = S * __expf(M - nm) + ss[w] * __expf(sm[w] - nm);
      M = nm;
    }
    int tgt = y[row];
    float rl = 0.f;
    if (tgt >= 0) rl = (M + __logf(S)) - L[tgt];
    rowloss[row] = rl;
  }
}

__global__ __launch_bounds__(256) void k_loss_final(
    const float* __restrict__ rowloss, const int* __restrict__ y,
    float* __restrict__ out)
{
  const int tid = threadIdx.x;
  float s = 0.f, c = 0.f;
  for (int i = tid; i < B_SZ * T_SZ; i += 256) {
    if (y[i] != -1) { s += rowloss[i]; c += 1.f; }
  }
  for (int off = 32; off > 0; off >>= 1) { s += __shfl_xor(s, off); c += __shfl_xor(c, off); }
  __shared__ float as_[4], ac_[4];
  const int wvi = tid >> 6, ln = tid & 63;
  if (ln == 0) { as_[wvi] = s; ac_[wvi] = c; }
  __syncthreads();
  if (tid == 0) {
    float S = as_[0] + as_[1] + as_[2] + as_[3];
    float C = ac_[0] + ac_[1] + ac_[2] + ac_[3];
    out[0] = S / fmaxf(C, 1.f);
  }
}

// ---------------- launch ----------------------------------------------------
extern "C" void kernel_launch(void* const* d_in, const int* in_sizes, int n_in,
                              void* d_out, int out_size, void* d_ws, size_t ws_size,
                              hipStream_t stream) {
  (void)in_sizes; (void)n_in; (void)ws_size;
  const int* x = (const int*)d_in[0];
  const int* y = (const int*)d_in[1];
  const float* E = (const float*)d_in[2];
  const float* Wih0 = (const float*)d_in[3];
  const float* Whh0 = (const float*)d_in[4];
  const float* Wih1 = (const float*)d_in[5];
  const float* Whh1 = (const float*)d_in[6];
  const float* Wfc = (const float*)d_in[7];
  const float* bfc = (const float*)d_in[8];
  char* ws = (char*)d_ws;
  // workspace layout (bytes)
  unsigned short* WfcT  = (unsigned short*)(ws + 0ULL);            // 50304*1024*2
  unsigned short* Wih0T = (unsigned short*)(ws + 103022592ULL);    // 1024*512*2
  unsigned short* Wih1T = (unsigned short*)(ws + 104071168ULL);    // 1024*1024*2
  unsigned short* XE    = (unsigned short*)(ws + 106168320ULL);    // 4096*512*2
  unsigned short* U0    = (unsigned short*)(ws + 110362624ULL);    // 4096*1024*2
  unsigned short* YS0   = (unsigned short*)(ws + 118751232ULL);    // 4096*1024*2
  unsigned short* U1    = (unsigned short*)(ws + 127139840ULL);    // 4096*1024*2
  unsigned short* FEATS = (unsigned short*)(ws + 135528448ULL);    // 4096*1024*2
  float* ROWLOSS        = (float*)(ws + 143917056ULL);             // 4096*4
  float* H0             = (float*)(ws + 143933440ULL);             // 2*8192*4
  float* H1             = (float*)(ws + 143998976ULL);             // 2*8192*4
  unsigned int* CNT0    = (unsigned int*)(ws + 144064512ULL);
  unsigned int* CNT1    = CNT0 + 32;                               // next line
  float* logits = (float*)d_out;
  float* lossp = logits + (size_t)(out_size - 1);

  // zero h ping-pong buffers + barrier counters (fresh every launch/replay)
  hipMemsetAsync(ws + 143933440ULL, 0, 131328, stream);

  // weight transposes (f32 [K][N] -> bf16 [Npad][K])
  k_transpose<<<dim3(32, 16), dim3(32, 8), 0, stream>>>(Wih0, Wih0T, 512, 1024, 1024);
  k_transpose<<<dim3(32, 32), dim3(32, 8), 0, stream>>>(Wih1, Wih1T, 1024, 1024, 1024);
  k_transpose<<<dim3(1572, 32), dim3(32, 8), 0, stream>>>(Wfc, WfcT, 1024, V_SZ, V_PAD);

  // embedding gather (time-major bf16)
  k_embed<<<4096, 128, 0, stream>>>(x, E, XE);

  // U0 = XE @ Wih0  (bf16 out, time-major rows)
  k_gemm<true, false><<<dim3(8, 32), 256, 0, stream>>>(XE, Wih0T, U0, nullptr,
                                                       1024, 512, 512, 512, 1024);
  // layer 0 recurrence -> ys0 time-major
  k_rec<<<REC_WGS, REC_THREADS, 0, stream>>>(U0, Whh0, YS0, 8192, 1024, H0, CNT0);
  // U1 = ys0 @ Wih1
  k_gemm<true, false><<<dim3(8, 32), 256, 0, stream>>>(YS0, Wih1T, U1, nullptr,
                                                       1024, 1024, 1024, 1024, 1024);
  // layer 1 recurrence -> feats batch-major (rows b*T+t)
  k_rec<<<REC_WGS, REC_THREADS, 0, stream>>>(U1, Whh1, FEATS, 1024, 524288, H1, CNT1);
  // logits = feats @ Wfc + bfc  (f32 out into d_out)
  k_gemm<false, true><<<dim3(393, 32), 256, 0, stream>>>(FEATS, WfcT, logits, bfc,
                                                         V_SZ, 1024, 1024, 1024, V_SZ);
  // loss
  k_loss_row<<<4096, 256, 0, stream>>>(logits, y, ROWLOSS);
  k_loss_final<<<1, 256, 0, stream>>>(ROWLOSS, y, lossp);
}

// Round 2
// 7162.964 us; speedup vs baseline: 1.6629x; 1.6629x over previous
//
#include <hip/hip_runtime.h>

// ---------------------------------------------------------------------------
// 2-layer Elman RNN LM forward on MI355X.
// transposes (f32->bf16 [N][K]) -> embed -> U0 GEMM -> rec L0 (MFMA, flags) ->
// U1 GEMM -> rec L1 -> logits GEMM (bf16 MFMA, f32+bias) -> logsumexp -> loss.
// Recurrence: 16 persistent WGs x 4 waves; Whh held in VGPRs as MFMA B-frags;
// h (bf16) exchanged via LLC with per-WG monotonic flags (no atomic RMW).
// ---------------------------------------------------------------------------

#define H_DIM 1024
#define B_SZ 8
#define T_SZ 512
#define V_SZ 50257
#define V_PAD 50304

typedef __attribute__((ext_vector_type(8))) short bf16x8;
typedef __attribute__((ext_vector_type(4))) float f32x4;

__device__ __forceinline__ unsigned short f2bf(float f) {
  unsigned int u = __float_as_uint(f);
  u += 0x7fffu + ((u >> 16) & 1u);   // round-to-nearest-even
  return (unsigned short)(u >> 16);
}
__device__ __forceinline__ float bf2f(unsigned short h) {
  return __uint_as_float(((unsigned int)h) << 16);
}

__device__ __forceinline__ void gload_lds16(const void* g, void* l) {
  __builtin_amdgcn_global_load_lds(
      (const __attribute__((address_space(1))) void*)g,
      (__attribute__((address_space(3))) void*)l, 16, 0, 0);
}

// ---------------- transpose f32 [K][N] -> bf16 [Npad][K] (zero-fill pad) ----
__global__ __launch_bounds__(256) void k_transpose(
    const float* __restrict__ in, unsigned short* __restrict__ out,
    int K, int N, int Npad)
{
  __shared__ float tile[32][33];
  const int n0 = blockIdx.x * 32, k0 = blockIdx.y * 32;
  const int tx = threadIdx.x, ty = threadIdx.y;
#pragma unroll
  for (int jj = 0; jj < 4; ++jj) {
    int k = k0 + ty + jj * 8, n = n0 + tx;
    tile[ty + jj * 8][tx] = (n < N) ? in[(size_t)k * N + n] : 0.f;
  }
  __syncthreads();
#pragma unroll
  for (int jj = 0; jj < 4; ++jj) {
    int n = n0 + ty + jj * 8, k = k0 + tx;
    if (n < Npad) out[(size_t)n * K + k] = f2bf((n < N) ? tile[tx][ty + jj * 8] : 0.f);
  }
}

// ---------------- embedding gather -> time-major bf16 [T*B][512] ------------
__global__ __launch_bounds__(128) void k_embed(
    const int* __restrict__ x, const float* __restrict__ E,
    unsigned short* __restrict__ xe)
{
  const int r = blockIdx.x;            // time-major row t*8+b
  const int t = r >> 3, b = r & 7;
  const int tok = x[b * T_SZ + t];
  const float4 v = ((const float4*)(E + (size_t)tok * 512))[threadIdx.x];
  ushort4 o;
  o.x = f2bf(v.x); o.y = f2bf(v.y); o.z = f2bf(v.z); o.w = f2bf(v.w);
  *((ushort4*)(xe + (size_t)r * 512) + threadIdx.x) = o;
}

// ---------------- bf16 MFMA GEMM: C[M][N] = A[M][K] @ Bt[N][K]^T (+bias) ----
template <bool BF16_OUT, bool BIAS>
__global__ __launch_bounds__(256) void k_gemm(
    const unsigned short* __restrict__ A, const unsigned short* __restrict__ Bt,
    void* __restrict__ Cout, const float* __restrict__ bias,
    int Nvalid, int K, int lda, int ldb, int ldc)
{
  __shared__ unsigned short As[8192];
  __shared__ unsigned short Bs[8192];
  const int tid = threadIdx.x;
  const int n0 = blockIdx.x * 128;
  const int m0 = blockIdx.y * 128;
  const int lane = tid & 63;
  const int wv = tid >> 6;
  const int wm = wv >> 1, wn = wv & 1;
  const int ln = lane & 15, cc = lane >> 4;
  f32x4 acc[4][4] = {};
  const int rr = tid >> 3;
  const int cb = (tid & 7) << 4;

  for (int kb = 0; kb < K; kb += 64) {
    __syncthreads();
#pragma unroll
    for (int is = 0; is < 4; ++is) {
      int r = is * 32 + rr;
      int sb = cb ^ ((r & 7) << 4);
      gload_lds16((const char*)(A + (size_t)(m0 + r) * lda + kb) + sb,
                  &As[(is * 32 + 8 * wv) * 64]);
    }
#pragma unroll
    for (int is = 0; is < 4; ++is) {
      int r = is * 32 + rr;
      int sb = cb ^ ((r & 7) << 4);
      gload_lds16((const char*)(Bt + (size_t)(n0 + r) * ldb + kb) + sb,
                  &Bs[(is * 32 + 8 * wv) * 64]);
    }
    __syncthreads();
#pragma unroll
    for (int kk = 0; kk < 2; ++kk) {
      bf16x8 af[4], bfr[4];
      const int kslot = kk * 64 + cc * 16;
#pragma unroll
      for (int mi = 0; mi < 4; ++mi) {
        int ra = wm * 64 + mi * 16 + ln;
        af[mi] = *(const bf16x8*)((const char*)As + ra * 128 + (kslot ^ ((ra & 7) << 4)));
      }
#pragma unroll
      for (int ni = 0; ni < 4; ++ni) {
        int rb = wn * 64 + ni * 16 + ln;
        bfr[ni] = *(const bf16x8*)((const char*)Bs + rb * 128 + (kslot ^ ((rb & 7) << 4)));
      }
#pragma unroll
      for (int mi = 0; mi < 4; ++mi)
#pragma unroll
        for (int ni = 0; ni < 4; ++ni)
          acc[mi][ni] = __builtin_amdgcn_mfma_f32_16x16x32_bf16(af[mi], bfr[ni], acc[mi][ni], 0, 0, 0);
    }
  }
#pragma unroll
  for (int ni = 0; ni < 4; ++ni) {
    const int col = n0 + wn * 64 + ni * 16 + ln;
    const bool cok = col < Nvalid;
    float bv = 0.f;
    if (BIAS && cok) bv = bias[col];
#pragma unroll
    for (int mi = 0; mi < 4; ++mi) {
#pragma unroll
      for (int i = 0; i < 4; ++i) {
        if (cok) {
          const int rowg = m0 + wm * 64 + mi * 16 + cc * 4 + i;
          if (BF16_OUT)
            ((unsigned short*)Cout)[(size_t)rowg * ldc + col] = f2bf(acc[mi][ni][i]);
          else
            ((float*)Cout)[(size_t)rowg * ldc + col] = acc[mi][ni][i] + bv;
        }
      }
    }
  }
}

// ---------------- persistent MFMA recurrence -------------------------------
// h_t = tanh(u_t + h_{t-1} @ Whh).  16 WGs x 256 thr (4 waves); wave owns 16
// cols; Whh slice lives in 128 VGPRs as B-frags. h bf16 [8][1024] in global
// (uint pairs), staged per step into XOR-swizzled LDS. Per-WG monotonic flag
// barrier (no RMW): h stores -> vmcnt(0) -> barrier -> flag = t+1.
__global__ __launch_bounds__(256, 1) void k_rec2(
    const unsigned short* __restrict__ U, const float* __restrict__ Whh,
    unsigned short* __restrict__ ys, int ost_t, int ost_b,
    unsigned int* __restrict__ hbuf,    // 2 * 4096 uints, zeroed per launch
    unsigned int* __restrict__ flags)   // 16 flags, stride 32 uints, zeroed
{
  __shared__ unsigned int hs[4096];     // [8 rows][512 uint pairs], swizzled
  const int tid = threadIdx.x;
  const int lane = tid & 63;
  const int wv = tid >> 6;              // 0..3
  const int ln = lane & 15, cc = lane >> 4;
  const int n0 = blockIdx.x * 64 + wv * 16;
  const int col = n0 + ln;
  const int r = ln & 7;                 // A rows 8-15 duplicate 0-7 (discarded)

  // ---- one-time: load this wave's Whh slice into B-fragments (VGPRs) ----
  bf16x8 bw[32];
#pragma unroll
  for (int kc = 0; kc < 32; ++kc) {
    const float* wp = Whh + (size_t)(kc * 32 + cc * 8) * H_DIM + col;
    bf16x8 v;
#pragma unroll
    for (int q = 0; q < 8; ++q) v[q] = (short)f2bf(wp[(size_t)q * H_DIM]);
    bw[kc] = v;
  }

  for (int t = 0; t < T_SZ; ++t) {
    // U prefetch (independent of h, hides under poll)
    unsigned short uv[4] = {0, 0, 0, 0};
    if (cc < 2) {
#pragma unroll
      for (int i = 0; i < 4; ++i)
        uv[i] = U[(size_t)(t * B_SZ + cc * 4 + i) * H_DIM + col];
    }
    // parallel flag poll: thread i watches writer-WG i
    if (tid < 16) {
      while (__hip_atomic_load(flags + tid * 32, __ATOMIC_ACQUIRE,
                               __HIP_MEMORY_SCOPE_AGENT) < (unsigned)t)
        __builtin_amdgcn_s_sleep(1);
    }
    __syncthreads();                    // flags ok; prev-step LDS reads done
    // stage h (bf16 pairs) LLC -> LDS, swizzled
    const unsigned int* hg = hbuf + (t & 1) * 4096;
#pragma unroll
    for (int q = 0; q < 16; ++q) {
      int idx = q * 256 + tid;
      unsigned int v = __hip_atomic_load(hg + idx, __ATOMIC_RELAXED,
                                         __HIP_MEMORY_SCOPE_AGENT);
      int row = idx >> 9, ku = idx & 511;
      hs[(row * 512 + ku) ^ (row << 2)] = v;
    }
    __syncthreads();
    // 32 chained MFMAs (2 independent chains)
    f32x4 acc0 = {}, acc1 = {};
    const char* hb = (const char*)hs;
#pragma unroll
    for (int kc = 0; kc < 32; kc += 2) {
      bf16x8 a0 = *(const bf16x8*)(hb + ((r * 2048 + kc * 64 + cc * 16) ^ (r << 4)));
      bf16x8 a1 = *(const bf16x8*)(hb + ((r * 2048 + (kc + 1) * 64 + cc * 16) ^ (r << 4)));
      acc0 = __builtin_amdgcn_mfma_f32_16x16x32_bf16(a0, bw[kc], acc0, 0, 0, 0);
      acc1 = __builtin_amdgcn_mfma_f32_16x16x32_bf16(a1, bw[kc + 1], acc1, 0, 0, 0);
    }
    // epilogue: rows 0..7 live in lanes cc<2 (row = cc*4+i, col = n0+ln)
    float hv[4] = {0.f, 0.f, 0.f, 0.f};
    if (cc < 2) {
#pragma unroll
      for (int i = 0; i < 4; ++i)
        hv[i] = tanhf(acc0[i] + acc1[i] + bf2f(uv[i]));
    }
    unsigned int wpk[4];
#pragma unroll
    for (int i = 0; i < 4; ++i) {
      float pv = __shfl_xor(hv[i], 1);
      wpk[i] = (unsigned)f2bf(hv[i]) | ((unsigned)f2bf(pv) << 16);
    }
    unsigned int* hn = hbuf + ((t + 1) & 1) * 4096;
    const bool wr = (cc < 2) && !(ln & 1);
    if (wr) {
#pragma unroll
      for (int i = 0; i < 4; ++i)
        __hip_atomic_store(hn + (cc * 4 + i) * 512 + (col >> 1), wpk[i],
                           __ATOMIC_RELAXED, __HIP_MEMORY_SCOPE_AGENT);
    }
    asm volatile("s_waitcnt vmcnt(0)" ::: "memory");
    __syncthreads();                    // all h stores of this WG are at LLC
    if (tid == 0)
      __hip_atomic_store(flags + blockIdx.x * 32, (unsigned)(t + 1),
                         __ATOMIC_RELAXED, __HIP_MEMORY_SCOPE_AGENT);
    // ys stores drain in the background of the next poll
    if (wr) {
#pragma unroll
      for (int i = 0; i < 4; ++i)
        *(unsigned int*)(ys + (size_t)t * ost_t + (size_t)(cc * 4 + i) * ost_b + col) = wpk[i];
    }
  }
}

// ---------------- per-row online logsumexp -> rowloss ----------------------
__global__ __launch_bounds__(256) void k_loss_row(
    const float* __restrict__ logits, const int* __restrict__ y,
    float* __restrict__ rowloss)
{
  const int row = blockIdx.x;          // = b*T + t, matches y flat index
  const int tid = threadIdx.x;
  const float* L = logits + (size_t)row * V_SZ;
  float m = -3.4e38f, s = 0.f;
  for (int i = tid; i < V_SZ; i += 256) {
    float v = L[i];
    if (v > m) { s = s * __expf(m - v) + 1.f; m = v; }
    else s += __expf(v - m);
  }
  for (int off = 32; off > 0; off >>= 1) {
    float mo = __shfl_xor(m, off);
    float so = __shfl_xor(s, off);
    float nm = fmaxf(m, mo);
    s = s * __expf(m - nm) + so * __expf(mo - nm);
    m = nm;
  }
  __shared__ float sm[4], ss[4];
  const int wvi = tid >> 6, lnn = tid & 63;
  if (lnn == 0) { sm[wvi] = m; ss[wvi] = s; }
  __syncthreads();
  if (tid == 0) {
    float M = sm[0], S = ss[0];
    for (int w = 1; w < 4; ++w) {
      float nm = fmaxf(M, sm[w]);
      S = S * __expf(M - nm) + ss[w] * __expf(sm[w] - nm);
      M = nm;
    }
    int tgt = y[row];
    float rl = 0.f;
    if (tgt >= 0) rl = (M + __logf(S)) - L[tgt];
    rowloss[row] = rl;
  }
}

__global__ __launch_bounds__(256) void k_loss_final(
    const float* __restrict__ rowloss, const int* __restrict__ y,
    float* __restrict__ out)
{
  const int tid = threadIdx.x;
  float s = 0.f, c = 0.f;
  for (int i = tid; i < B_SZ * T_SZ; i += 256) {
    if (y[i] != -1) { s += rowloss[i]; c += 1.f; }
  }
  for (int off = 32; off > 0; off >>= 1) { s += __shfl_xor(s, off); c += __shfl_xor(c, off); }
  __shared__ float as_[4], ac_[4];
  const int wvi = tid >> 6, lnn = tid & 63;
  if (lnn == 0) { as_[wvi] = s; ac_[wvi] = c; }
  __syncthreads();
  if (tid == 0) {
    float S = as_[0] + as_[1] + as_[2] + as_[3];
    float C = ac_[0] + ac_[1] + ac_[2] + ac_[3];
    out[0] = S / fmaxf(C, 1.f);
  }
}

// ---------------- launch ----------------------------------------------------
extern "C" void kernel_launch(void* const* d_in, const int* in_sizes, int n_in,
                              void* d_out, int out_size, void* d_ws, size_t ws_size,
                              hipStream_t stream) {
  (void)in_sizes; (void)n_in; (void)ws_size;
  const int* x = (const int*)d_in[0];
  const int* y = (const int*)d_in[1];
  const float* E = (const float*)d_in[2];
  const float* Wih0 = (const float*)d_in[3];
  const float* Whh0 = (const float*)d_in[4];
  const float* Wih1 = (const float*)d_in[5];
  const float* Whh1 = (const float*)d_in[6];
  const float* Wfc = (const float*)d_in[7];
  const float* bfc = (const float*)d_in[8];
  char* ws = (char*)d_ws;
  // workspace layout (bytes)
  unsigned short* WfcT  = (unsigned short*)(ws + 0ULL);            // 50304*1024*2
  unsigned short* Wih0T = (unsigned short*)(ws + 103022592ULL);    // 1024*512*2
  unsigned short* Wih1T = (unsigned short*)(ws + 104071168ULL);    // 1024*1024*2
  unsigned short* XE    = (unsigned short*)(ws + 106168320ULL);    // 4096*512*2
  unsigned short* U0    = (unsigned short*)(ws + 110362624ULL);    // 4096*1024*2
  unsigned short* YS0   = (unsigned short*)(ws + 118751232ULL);    // 4096*1024*2
  unsigned short* U1    = (unsigned short*)(ws + 127139840ULL);    // 4096*1024*2
  unsigned short* FEATS = (unsigned short*)(ws + 135528448ULL);    // 4096*1024*2
  float* ROWLOSS        = (float*)(ws + 143917056ULL);             // 4096*4
  unsigned int* H0u     = (unsigned int*)(ws + 143933440ULL);      // 2*4096*4
  unsigned int* FL0     = (unsigned int*)(ws + 143966208ULL);      // 16*32*4
  unsigned int* H1u     = (unsigned int*)(ws + 143968256ULL);      // 2*4096*4
  unsigned int* FL1     = (unsigned int*)(ws + 144001024ULL);      // 16*32*4
  float* logits = (float*)d_out;
  float* lossp = logits + (size_t)(out_size - 1);

  // zero h ping-pong buffers + flags (fresh every launch/replay)
  hipMemsetAsync(ws + 143933440ULL, 0, 69632, stream);

  // weight transposes for GEMM B-operands (f32 [K][N] -> bf16 [Npad][K])
  k_transpose<<<dim3(32, 16), dim3(32, 8), 0, stream>>>(Wih0, Wih0T, 512, 1024, 1024);
  k_transpose<<<dim3(32, 32), dim3(32, 8), 0, stream>>>(Wih1, Wih1T, 1024, 1024, 1024);
  k_transpose<<<dim3(1572, 32), dim3(32, 8), 0, stream>>>(Wfc, WfcT, 1024, V_SZ, V_PAD);

  // embedding gather (time-major bf16)
  k_embed<<<4096, 128, 0, stream>>>(x, E, XE);

  // U0 = XE @ Wih0  (bf16 out, time-major rows)
  k_gemm<true, false><<<dim3(8, 32), 256, 0, stream>>>(XE, Wih0T, U0, nullptr,
                                                       1024, 512, 512, 512, 1024);
  // layer 0 recurrence -> ys0 time-major
  k_rec2<<<16, 256, 0, stream>>>(U0, Whh0, YS0, 8192, 1024, H0u, FL0);
  // U1 = ys0 @ Wih1
  k_gemm<true, false><<<dim3(8, 32), 256, 0, stream>>>(YS0, Wih1T, U1, nullptr,
                                                       1024, 1024, 1024, 1024, 1024);
  // layer 1 recurrence -> feats batch-major (rows b*T+t)
  k_rec2<<<16, 256, 0, stream>>>(U1, Whh1, FEATS, 1024, 524288, H1u, FL1);
  // logits = feats @ Wfc + bfc  (f32 out into d_out)
  k_gemm<false, true><<<dim3(393, 32), 256, 0, stream>>>(FEATS, WfcT, logits, bfc,
                                                         V_SZ, 1024, 1024, 1024, V_SZ);
  // loss
  k_loss_row<<<4096, 256, 0, stream>>>(logits, y, ROWLOSS);
  k_loss_final<<<1, 256, 0, stream>>>(ROWLOSS, y, lossp);
}

// Round 3
// 4328.400 us; speedup vs baseline: 2.7520x; 1.6549x over previous
//
#include <hip/hip_runtime.h>

// ---------------------------------------------------------------------------
// 2-layer Elman RNN LM forward on MI355X.
// transposes (f32->bf16 [N][K]) -> embed -> U0 GEMM -> FUSED rec L0+L1
// (persistent, per-wave flags, MFMA, weights-in-VGPR) -> logits GEMM
// (bf16 MFMA, f32+bias) -> row logsumexp -> mean loss.
// Fused rec: 32 WGs x 4 waves. WGs 0-15 = layer0, 16-31 = layer1 (lags by 1
// tick; consumes h0 broadcast directly, concat K=2048 with [Wih1;Whh1] in
// 256 VGPRs). Per-wave monotonic flags; relaxed polls + one acquire fence;
// wave-private LDS staging via global_load_lds (no intra-WG barriers).
// ---------------------------------------------------------------------------

#define H_DIM 1024
#define B_SZ 8
#define T_SZ 512
#define V_SZ 50257
#define V_PAD 50304

typedef __attribute__((ext_vector_type(8))) short bf16x8;
typedef __attribute__((ext_vector_type(4))) float f32x4;

__device__ __forceinline__ unsigned short f2bf(float f) {
  unsigned int u = __float_as_uint(f);
  u += 0x7fffu + ((u >> 16) & 1u);   // round-to-nearest-even
  return (unsigned short)(u >> 16);
}
__device__ __forceinline__ float bf2f(unsigned short h) {
  return __uint_as_float(((unsigned int)h) << 16);
}

__device__ __forceinline__ void gload_lds16(const void* g, void* l) {
  __builtin_amdgcn_global_load_lds(
      (const __attribute__((address_space(1))) void*)g,
      (__attribute__((address_space(3))) void*)l, 16, 0, 0);
}

// ---------------- transpose f32 [K][N] -> bf16 [Npad][K] (zero-fill pad) ----
__global__ __launch_bounds__(256) void k_transpose(
    const float* __restrict__ in, unsigned short* __restrict__ out,
    int K, int N, int Npad)
{
  __shared__ float tile[32][33];
  const int n0 = blockIdx.x * 32, k0 = blockIdx.y * 32;
  const int tx = threadIdx.x, ty = threadIdx.y;
#pragma unroll
  for (int jj = 0; jj < 4; ++jj) {
    int k = k0 + ty + jj * 8, n = n0 + tx;
    tile[ty + jj * 8][tx] = (n < N) ? in[(size_t)k * N + n] : 0.f;
  }
  __syncthreads();
#pragma unroll
  for (int jj = 0; jj < 4; ++jj) {
    int n = n0 + ty + jj * 8, k = k0 + tx;
    if (n < Npad) out[(size_t)n * K + k] = f2bf((n < N) ? tile[tx][ty + jj * 8] : 0.f);
  }
}

// ---------------- embedding gather -> time-major bf16 [T*B][512] ------------
__global__ __launch_bounds__(128) void k_embed(
    const int* __restrict__ x, const float* __restrict__ E,
    unsigned short* __restrict__ xe)
{
  const int r = blockIdx.x;            // time-major row t*8+b
  const int t = r >> 3, b = r & 7;
  const int tok = x[b * T_SZ + t];
  const float4 v = ((const float4*)(E + (size_t)tok * 512))[threadIdx.x];
  ushort4 o;
  o.x = f2bf(v.x); o.y = f2bf(v.y); o.z = f2bf(v.z); o.w = f2bf(v.w);
  *((ushort4*)(xe + (size_t)r * 512) + threadIdx.x) = o;
}

// ---------------- bf16 MFMA GEMM: C[M][N] = A[M][K] @ Bt[N][K]^T (+bias) ----
template <bool BF16_OUT, bool BIAS>
__global__ __launch_bounds__(256) void k_gemm(
    const unsigned short* __restrict__ A, const unsigned short* __restrict__ Bt,
    void* __restrict__ Cout, const float* __restrict__ bias,
    int Nvalid, int K, int lda, int ldb, int ldc)
{
  __shared__ unsigned short As[8192];
  __shared__ unsigned short Bs[8192];
  const int tid = threadIdx.x;
  const int n0 = blockIdx.x * 128;
  const int m0 = blockIdx.y * 128;
  const int lane = tid & 63;
  const int wv = tid >> 6;
  const int wm = wv >> 1, wn = wv & 1;
  const int ln = lane & 15, cc = lane >> 4;
  f32x4 acc[4][4] = {};
  const int rr = tid >> 3;
  const int cb = (tid & 7) << 4;

  for (int kb = 0; kb < K; kb += 64) {
    __syncthreads();
#pragma unroll
    for (int is = 0; is < 4; ++is) {
      int r = is * 32 + rr;
      int sb = cb ^ ((r & 7) << 4);
      gload_lds16((const char*)(A + (size_t)(m0 + r) * lda + kb) + sb,
                  &As[(is * 32 + 8 * wv) * 64]);
    }
#pragma unroll
    for (int is = 0; is < 4; ++is) {
      int r = is * 32 + rr;
      int sb = cb ^ ((r & 7) << 4);
      gload_lds16((const char*)(Bt + (size_t)(n0 + r) * ldb + kb) + sb,
                  &Bs[(is * 32 + 8 * wv) * 64]);
    }
    __syncthreads();
#pragma unroll
    for (int kk = 0; kk < 2; ++kk) {
      bf16x8 af[4], bfr[4];
      const int kslot = kk * 64 + cc * 16;
#pragma unroll
      for (int mi = 0; mi < 4; ++mi) {
        int ra = wm * 64 + mi * 16 + ln;
        af[mi] = *(const bf16x8*)((const char*)As + ra * 128 + (kslot ^ ((ra & 7) << 4)));
      }
#pragma unroll
      for (int ni = 0; ni < 4; ++ni) {
        int rb = wn * 64 + ni * 16 + ln;
        bfr[ni] = *(const bf16x8*)((const char*)Bs + rb * 128 + (kslot ^ ((rb & 7) << 4)));
      }
#pragma unroll
      for (int mi = 0; mi < 4; ++mi)
#pragma unroll
        for (int ni = 0; ni < 4; ++ni)
          acc[mi][ni] = __builtin_amdgcn_mfma_f32_16x16x32_bf16(af[mi], bfr[ni], acc[mi][ni], 0, 0, 0);
    }
  }
#pragma unroll
  for (int ni = 0; ni < 4; ++ni) {
    const int col = n0 + wn * 64 + ni * 16 + ln;
    const bool cok = col < Nvalid;
    float bv = 0.f;
    if (BIAS && cok) bv = bias[col];
#pragma unroll
    for (int mi = 0; mi < 4; ++mi) {
#pragma unroll
      for (int i = 0; i < 4; ++i) {
        if (cok) {
          const int rowg = m0 + wm * 64 + mi * 16 + cc * 4 + i;
          if (BF16_OUT)
            ((unsigned short*)Cout)[(size_t)rowg * ldc + col] = f2bf(acc[mi][ni][i]);
          else
            ((float*)Cout)[(size_t)rowg * ldc + col] = acc[mi][ni][i] + bv;
        }
      }
    }
  }
}

// ---------------- fused persistent recurrence (both layers) -----------------
// ROLE 0: h0[t] = tanh(U0[t] + h0[t-1] @ Whh0)
// ROLE 1: h1[t] = tanh(h0[t] @ Wih1 + h1[t-1] @ Whh1)  -> FEATS
// Flags: 128 per-wave monotonic ints (stride 32 uints). Wave gw sets
// flags[gw]=t+1 after its h stores are LLC-acked. Poll: 2 gather loads/lane,
// relaxed, + acquire fence on exit. Staging: wave-private LDS, single-buffered
// (safe: only the owning wave writes/reads it, program order suffices).
template <int ROLE>
__device__ __forceinline__ void rec_body(
    const unsigned short* __restrict__ U0,
    const float* __restrict__ W0, const float* __restrict__ W1,
    unsigned short* __restrict__ feats,
    unsigned int* __restrict__ h0buf, unsigned int* __restrict__ h1buf,
    int* __restrict__ flags, char* myl, int wgl, int wv)
{
  constexpr int NF = ROLE ? 64 : 32;   // K/32 fragments
  const int lane = threadIdx.x & 63;
  const int ln = lane & 15, cc = lane >> 4;
  const int r = ln & 7;                // A rows 8-15 duplicate 0-7 (discarded)
  const int n0 = wgl * 64 + wv * 16;
  const int col = n0 + ln;
  const int gw = (ROLE * 16 + wgl) * 4 + wv;
  const int lswz = r << 4;

  // one-time: weight B-fragments into VGPRs (f32 -> bf16 on the fly)
  bf16x8 bw[NF];
#pragma unroll
  for (int kc = 0; kc < NF; ++kc) {
    const float* wp;
    if (ROLE == 0) wp = W0 + (size_t)(kc * 32 + cc * 8) * H_DIM + col;
    else wp = (kc < 32) ? W0 + (size_t)(kc * 32 + cc * 8) * H_DIM + col
                        : W1 + (size_t)((kc - 32) * 32 + cc * 8) * H_DIM + col;
    bf16x8 v;
#pragma unroll
    for (int q = 0; q < 8; ++q) v[q] = (short)f2bf(wp[(size_t)q * H_DIM]);
    bw[kc] = v;
  }

#pragma unroll 1
  for (int t = 0; t < T_SZ; ++t) {
    // U prefetch (ROLE 0 only; constant data, safe across the fence)
    unsigned short uva[4] = {0, 0, 0, 0};
    if (ROLE == 0 && cc < 2) {
#pragma unroll
      for (int i = 0; i < 4; ++i)
        uva[i] = U0[(size_t)(t * B_SZ + cc * 4 + i) * H_DIM + col];
    }
    // poll all 128 per-wave flags (lane L watches wave L of each role)
    {
      const int ta = ROLE ? t + 1 : t;       // L0-wave flags threshold
      const int tb = ROLE ? t : t - 1;       // L1-wave flags threshold
      const int* fa = flags + lane * 32;
      const int* fb = flags + (64 + lane) * 32;
      for (;;) {
        int va = __hip_atomic_load(fa, __ATOMIC_RELAXED, __HIP_MEMORY_SCOPE_AGENT);
        int vb = __hip_atomic_load(fb, __ATOMIC_RELAXED, __HIP_MEMORY_SCOPE_AGENT);
        if (__all(va >= ta && vb >= tb)) break;
        __builtin_amdgcn_s_sleep(1);
      }
      __builtin_amdgcn_fence(__ATOMIC_ACQUIRE, "agent");
      asm volatile("" ::: "memory");
    }
    // stage h into wave-private LDS; source pre-swizzled ^(r<<4), dest linear
    {
      const char* s0 = (const char*)(h0buf + ((ROLE ? (t + 1) : t) & 1) * 4096);
#pragma unroll
      for (int q = 0; q < 16; ++q) {
        int rq = q >> 1;
        int so = rq * 2048 + ((((q & 1) << 10) + lane * 16) ^ (rq << 4));
        gload_lds16(s0 + so, myl + q * 1024);
      }
      if (ROLE) {
        const char* s1 = (const char*)(h1buf + (t & 1) * 4096);
#pragma unroll
        for (int q = 0; q < 16; ++q) {
          int rq = q >> 1;
          int so = rq * 2048 + ((((q & 1) << 10) + lane * 16) ^ (rq << 4));
          gload_lds16(s1 + so, myl + 16384 + q * 1024);
        }
      }
      asm volatile("s_waitcnt vmcnt(0)" ::: "memory");
    }
    // MFMA: 4 chains, round-robin issue (dep distance 4)
    f32x4 ac[4] = {};
    constexpr int NQ = NF / 4;
#pragma unroll
    for (int j = 0; j < NQ; ++j) {
#pragma unroll
      for (int g = 0; g < 4; ++g) {
        const int kc = g * NQ + j;
        const int off = (kc >> 5) * 16384 +
            ((r * 2048 + (kc & 31) * 64 + cc * 16) ^ lswz);
        bf16x8 a = *(const bf16x8*)(myl + off);
        ac[g] = __builtin_amdgcn_mfma_f32_16x16x32_bf16(a, bw[kc], ac[g], 0, 0, 0);
      }
    }
    // epilogue: rows live in lanes cc<2 (row = cc*4+i, col = n0+ln)
    float hv[4] = {0.f, 0.f, 0.f, 0.f};
    if (cc < 2) {
#pragma unroll
      for (int i = 0; i < 4; ++i) {
        float s = ac[0][i] + ac[1][i] + ac[2][i] + ac[3][i];
        if (ROLE == 0) s += bf2f(uva[i]);
        hv[i] = tanhf(s);
      }
    }
    unsigned int wpk[4];
#pragma unroll
    for (int i = 0; i < 4; ++i) {
      float pv = __shfl_xor(hv[i], 1);
      wpk[i] = (unsigned)f2bf(hv[i]) | ((unsigned)f2bf(pv) << 16);
    }
    unsigned int* hn = (ROLE ? h1buf : h0buf) + ((t + 1) & 1) * 4096;
    const bool wr = (cc < 2) && !(ln & 1);
    if (wr) {
#pragma unroll
      for (int i = 0; i < 4; ++i)
        __hip_atomic_store(hn + (cc * 4 + i) * 512 + (col >> 1), wpk[i],
                           __ATOMIC_RELAXED, __HIP_MEMORY_SCOPE_AGENT);
    }
    asm volatile("s_waitcnt vmcnt(0)" ::: "memory");   // h stores LLC-acked
    if (lane == 0)
      __hip_atomic_store(flags + gw * 32, t + 1, __ATOMIC_RELAXED,
                         __HIP_MEMORY_SCOPE_AGENT);
    // FEATS stores drain in the background of the next poll
    if (ROLE == 1 && wr) {
#pragma unroll
      for (int i = 0; i < 4; ++i)
        *(unsigned int*)(feats + (size_t)(cc * 4 + i) * 524288 + t * 1024 + col) = wpk[i];
    }
  }
}

__global__ __launch_bounds__(256, 1) void k_recf(
    const unsigned short* __restrict__ U0,
    const float* __restrict__ Whh0, const float* __restrict__ Wih1,
    const float* __restrict__ Whh1, unsigned short* __restrict__ feats,
    unsigned int* __restrict__ h0buf, unsigned int* __restrict__ h1buf,
    int* __restrict__ flags)
{
  __shared__ char lds[131072];         // 4 waves x 32KB private
  const int wv = threadIdx.x >> 6;
  char* myl = lds + wv * 32768;
  if (blockIdx.x < 16)
    rec_body<0>(U0, Whh0, nullptr, nullptr, h0buf, h1buf, flags, myl,
                blockIdx.x, wv);
  else
    rec_body<1>(nullptr, Wih1, Whh1, feats, h0buf, h1buf, flags, myl,
                blockIdx.x - 16, wv);
}

// ---------------- per-row online logsumexp -> rowloss ----------------------
__global__ __launch_bounds__(256) void k_loss_row(
    const float* __restrict__ logits, const int* __restrict__ y,
    float* __restrict__ rowloss)
{
  const int row = blockIdx.x;          // = b*T + t, matches y flat index
  const int tid = threadIdx.x;
  const float* L = logits + (size_t)row * V_SZ;
  float m = -3.4e38f, s = 0.f;
  for (int i = tid; i < V_SZ; i += 256) {
    float v = L[i];
    if (v > m) { s = s * __expf(m - v) + 1.f; m = v; }
    else s += __expf(v - m);
  }
  for (int off = 32; off > 0; off >>= 1) {
    float mo = __shfl_xor(m, off);
    float so = __shfl_xor(s, off);
    float nm = fmaxf(m, mo);
    s = s * __expf(m - nm) + so * __expf(mo - nm);
    m = nm;
  }
  __shared__ float sm[4], ss[4];
  const int wvi = tid >> 6, lnn = tid & 63;
  if (lnn == 0) { sm[wvi] = m; ss[wvi] = s; }
  __syncthreads();
  if (tid == 0) {
    float M = sm[0], S = ss[0];
    for (int w = 1; w < 4; ++w) {
      float nm = fmaxf(M, sm[w]);
      S = S * __expf(M - nm) + ss[w] * __expf(sm[w] - nm);
      M = nm;
    }
    int tgt = y[row];
    float rl = 0.f;
    if (tgt >= 0) rl = (M + __logf(S)) - L[tgt];
    rowloss[row] = rl;
  }
}

__global__ __launch_bounds__(256) void k_loss_final(
    const float* __restrict__ rowloss, const int* __restrict__ y,
    float* __restrict__ out)
{
  const int tid = threadIdx.x;
  float s = 0.f, c = 0.f;
  for (int i = tid; i < B_SZ * T_SZ; i += 256) {
    if (y[i] != -1) { s += rowloss[i]; c += 1.f; }
  }
  for (int off = 32; off > 0; off >>= 1) { s += __shfl_xor(s, off); c += __shfl_xor(c, off); }
  __shared__ float as_[4], ac_[4];
  const int wvi = tid >> 6, lnn = tid & 63;
  if (lnn == 0) { as_[wvi] = s; ac_[wvi] = c; }
  __syncthreads();
  if (tid == 0) {
    float S = as_[0] + as_[1] + as_[2] + as_[3];
    float C = ac_[0] + ac_[1] + ac_[2] + ac_[3];
    out[0] = S / fmaxf(C, 1.f);
  }
}

// ---------------- launch ----------------------------------------------------
extern "C" void kernel_launch(void* const* d_in, const int* in_sizes, int n_in,
                              void* d_out, int out_size, void* d_ws, size_t ws_size,
                              hipStream_t stream) {
  (void)in_sizes; (void)n_in; (void)ws_size;
  const int* x = (const int*)d_in[0];
  const int* y = (const int*)d_in[1];
  const float* E = (const float*)d_in[2];
  const float* Wih0 = (const float*)d_in[3];
  const float* Whh0 = (const float*)d_in[4];
  const float* Wih1 = (const float*)d_in[5];
  const float* Whh1 = (const float*)d_in[6];
  const float* Wfc = (const float*)d_in[7];
  const float* bfc = (const float*)d_in[8];
  char* ws = (char*)d_ws;
  // workspace layout (bytes)
  unsigned short* WfcT  = (unsigned short*)(ws + 0ULL);            // 50304*1024*2
  unsigned short* Wih0T = (unsigned short*)(ws + 103022592ULL);    // 1024*512*2
  unsigned short* XE    = (unsigned short*)(ws + 106168320ULL);    // 4096*512*2
  unsigned short* U0    = (unsigned short*)(ws + 110362624ULL);    // 4096*1024*2
  unsigned short* FEATS = (unsigned short*)(ws + 135528448ULL);    // 4096*1024*2
  float* ROWLOSS        = (float*)(ws + 143917056ULL);             // 4096*4
  unsigned int* H0u     = (unsigned int*)(ws + 143933440ULL);      // 2*4096*4
  unsigned int* H1u     = (unsigned int*)(ws + 143966208ULL);      // 2*4096*4
  int* FLAGS            = (int*)(ws + 143998976ULL);               // 128*32*4
  float* logits = (float*)d_out;
  float* lossp = logits + (size_t)(out_size - 1);

  // zero h ping-pong buffers + flags (fresh every launch/replay)
  hipMemsetAsync(ws + 143933440ULL, 0, 81920, stream);

  // weight transposes for GEMM B-operands (f32 [K][N] -> bf16 [Npad][K])
  k_transpose<<<dim3(32, 16), dim3(32, 8), 0, stream>>>(Wih0, Wih0T, 512, 1024, 1024);
  k_transpose<<<dim3(1572, 32), dim3(32, 8), 0, stream>>>(Wfc, WfcT, 1024, V_SZ, V_PAD);

  // embedding gather (time-major bf16)
  k_embed<<<4096, 128, 0, stream>>>(x, E, XE);

  // U0 = XE @ Wih0  (bf16 out, time-major rows)
  k_gemm<true, false><<<dim3(8, 32), 256, 0, stream>>>(XE, Wih0T, U0, nullptr,
                                                       1024, 512, 512, 512, 1024);
  // fused recurrence: layer0 + layer1 pipelined -> FEATS (batch-major)
  k_recf<<<32, 256, 0, stream>>>(U0, Whh0, Wih1, Whh1, FEATS, H0u, H1u, FLAGS);

  // logits = feats @ Wfc + bfc  (f32 out into d_out)
  k_gemm<false, true><<<dim3(393, 32), 256, 0, stream>>>(FEATS, WfcT, logits, bfc,
                                                         V_SZ, 1024, 1024, 1024, V_SZ);
  // loss
  k_loss_row<<<4096, 256, 0, stream>>>(logits, y, ROWLOSS);
  k_loss_final<<<1, 256, 0, stream>>>(ROWLOSS, y, lossp);
}